// Round 9
// baseline (48.886 us; speedup 1.0000x reference)
//
#include <hip/hip_runtime.h>

// B=4, T=16, N=S=256, H=8, DK=DV=64, fp32 in/out.
// One block per (bt, h): 512 blocks x 512 threads (8 waves).
// Swapped QK^T (A=K, B=Q), no max-sub, scale*log2e folded into Q,
// both n-passes merged (K/V LDS fragments read once), permlane P exchange,
// V^T XOR bank-swizzle, depth-1 K/V ds_read prefetch, per-wave ks stagger.
// This round: (1) ALL 20 staging float4 loads batched into registers before
// any convert/LDS-write (one global-latency round, was ~4 register-starved
// rounds at VGPR=56); (2) PV operands swapped -> D[d][n] layout -> epilogue
// is 8 float4 stores (was 32 scattered dwords) and needs no rcp shfl.

typedef short short8 __attribute__((ext_vector_type(8)));
typedef float floatx4 __attribute__((ext_vector_type(4)));

__device__ __forceinline__ unsigned cvt_pk(float lo, float hi) {
  unsigned r;
  asm("v_cvt_pk_bf16_f32 %0, %1, %2" : "=v"(r) : "v"(lo), "v"(hi));
  return r;
}

constexpr int KSTR  = 72;    // Klds row stride in shorts (144 B)
constexpr int VSTRW = 132;   // Vt row stride in u32 words (528 B)

__global__ __launch_bounds__(512, 4) void attn_kernel(
    const float* __restrict__ Q, const float* __restrict__ K,
    const float* __restrict__ V, float* __restrict__ O) {
  __shared__ __align__(16) short Klds[256 * KSTR];       // 36864 B
  __shared__ __align__(16) unsigned Vt32[64 * VSTRW];    // 33792 B (70656 total)

  const int inst = blockIdx.x;
  const int h    = inst & 7;
  const int bt   = inst >> 3;
  const int base = bt * (256 * 512) + h * 64;
  const int tid  = threadIdx.x;

  const int wave = tid >> 6;
  const int lane = tid & 63;
  const int c    = lane & 15;
  const int g    = lane >> 4;

  // ---- issue ALL staging loads first: 8 K + 8 V + 4 Q float4 ----
  const int c4 = tid & 15;
  const int sQ = tid >> 4;         // 0..31
  float4 kv[8], vv0[4], vv1[4], qv[4];
  {
    const float* Kb = K + base;
    #pragma unroll
    for (int i = 0; i < 8; ++i)
      kv[i] = *reinterpret_cast<const float4*>(Kb + (i * 32 + sQ) * 512 + c4 * 4);
    const float* Vb = V + base;
    #pragma unroll
    for (int i = 0; i < 4; ++i) {
      int sp = i * 32 + sQ;
      vv0[i] = *reinterpret_cast<const float4*>(Vb + (2 * sp) * 512 + c4 * 4);
      vv1[i] = *reinterpret_cast<const float4*>(Vb + (2 * sp + 1) * 512 + c4 * 4);
    }
    #pragma unroll
    for (int p = 0; p < 2; ++p)
      #pragma unroll
      for (int ks2 = 0; ks2 < 2; ++ks2)
        qv[p * 2 + ks2] = *reinterpret_cast<const float4*>(
            Q + base + (p * 128 + wave * 16 + c) * 512 + ks2 * 32 + g * 8 +
            ((lane >> 2) & 1) * 0);   // plain address; see qf build below
  }

  // ---- stage K: 256x64 fp32 -> bf16 LDS ----
  #pragma unroll
  for (int i = 0; i < 8; ++i) {
    uint2 w;
    w.x = cvt_pk(kv[i].x, kv[i].y);
    w.y = cvt_pk(kv[i].z, kv[i].w);
    *reinterpret_cast<uint2*>(&Klds[(i * 32 + sQ) * KSTR + c4 * 4]) = w;
  }
  // ---- stage V^T with XOR bank swizzle ----
  #pragma unroll
  for (int i = 0; i < 4; ++i) {
    int sp  = i * 32 + sQ;
    int spw = sp ^ ((c4 & 7) << 2);
    #pragma unroll
    for (int k = 0; k < 4; ++k)
      Vt32[(c4 * 4 + k) * VSTRW + spw] = cvt_pk((&vv0[i].x)[k], (&vv1[i].x)[k]);
  }

  // ---- Q fragments for BOTH passes, scaled by 0.125*log2(e) ----
  const float SCQ = 0.125f * 1.4426950408889634f;
  short8 qf[2][2];
  #pragma unroll
  for (int p = 0; p < 2; ++p)
    #pragma unroll
    for (int ks2 = 0; ks2 < 2; ++ks2) {
      float4 a = qv[p * 2 + ks2];
      // second half of the 8 elems comes from the adjacent 4 floats:
      // reload pattern replaced by a single float4 pair load; to keep one
      // float4 per (p,ks2) we fetch the other half here (L1/L2-hot).
      float4 b = *reinterpret_cast<const float4*>(
          Q + base + (p * 128 + wave * 16 + c) * 512 + ks2 * 32 + g * 8 + 4);
      union { unsigned u[4]; short8 s; } t;
      t.u[0] = cvt_pk(a.x * SCQ, a.y * SCQ);
      t.u[1] = cvt_pk(a.z * SCQ, a.w * SCQ);
      t.u[2] = cvt_pk(b.x * SCQ, b.y * SCQ);
      t.u[3] = cvt_pk(b.z * SCQ, b.w * SCQ);
      qf[p][ks2] = t.s;
    }
  __syncthreads();

#define KREAD(t, half) \
  (*reinterpret_cast<const short8*>(&Klds[((t) * 16 + c) * KSTR + (half) * 32 + g * 8]))
#define VREAD(dt, ks) \
  (*reinterpret_cast<const short8*>(reinterpret_cast<const short*>( \
      &Vt32[((dt) * 16 + c) * VSTRW + \
            (((ks) * 16 + 4 * g) ^ (16 * ((dt) & 1) + (c & 12)))])))

  floatx4 ao[2][4];
  #pragma unroll
  for (int p = 0; p < 2; ++p)
    #pragma unroll
    for (int dt = 0; dt < 4; ++dt) ao[p][dt] = floatx4{0.f, 0.f, 0.f, 0.f};
  float ps[2][4] = {{0.f, 0.f, 0.f, 0.f}, {0.f, 0.f, 0.f, 0.f}};

  const int ksW = wave & 7;   // per-wave stagger: de-convoy LDS access
  short8 kfa = KREAD(2 * ksW, 0);
  short8 kfb = KREAD(2 * ksW, 1);

  #pragma unroll
  for (int kk = 0; kk < 8; ++kk) {
    const int ks  = (kk + ksW) & 7;
    const int ksn = (ks + 1) & 7;
    unsigned pk2[2][2][2];   // [pass][tt][m]

    // -- unit tt=0 (t = 2ks): consume kfa/kfb, prefetch t = 2ks+1 --
    {
      short8 ka = kfa, kb = kfb;
      kfa = KREAD(2 * ks + 1, 0);
      kfb = KREAD(2 * ks + 1, 1);
      #pragma unroll
      for (int p = 0; p < 2; ++p) {
        floatx4 z = {0.f, 0.f, 0.f, 0.f};
        floatx4 a0 = __builtin_amdgcn_mfma_f32_16x16x32_bf16(ka, qf[p][0], z, 0, 0, 0);
        floatx4 a1 = __builtin_amdgcn_mfma_f32_16x16x32_bf16(kb, qf[p][1], z, 0, 0, 0);
        float e0 = exp2f(a0[0] + a1[0]);
        float e1 = exp2f(a0[1] + a1[1]);
        float e2 = exp2f(a0[2] + a1[2]);
        float e3 = exp2f(a0[3] + a1[3]);
        ps[p][0] += e0; ps[p][1] += e1; ps[p][2] += e2; ps[p][3] += e3;
        pk2[p][0][0] = cvt_pk(e0, e1);
        pk2[p][0][1] = cvt_pk(e2, e3);
      }
    }

    // -- V prefetch for this ks (latency hidden under tt=1 compute) --
    short8 vf0 = VREAD(0, ks);
    short8 vf1 = VREAD(1, ks);
    short8 vf2 = VREAD(2, ks);
    short8 vf3 = VREAD(3, ks);

    // -- unit tt=1 (t = 2ks+1): consume kfa/kfb, prefetch next unit --
    {
      short8 ka = kfa, kb = kfb;
      kfa = KREAD(2 * ksn, 0);
      kfb = KREAD(2 * ksn, 1);
      #pragma unroll
      for (int p = 0; p < 2; ++p) {
        floatx4 z = {0.f, 0.f, 0.f, 0.f};
        floatx4 a0 = __builtin_amdgcn_mfma_f32_16x16x32_bf16(ka, qf[p][0], z, 0, 0, 0);
        floatx4 a1 = __builtin_amdgcn_mfma_f32_16x16x32_bf16(kb, qf[p][1], z, 0, 0, 0);
        float e0 = exp2f(a0[0] + a1[0]);
        float e1 = exp2f(a0[1] + a1[1]);
        float e2 = exp2f(a0[2] + a1[2]);
        float e3 = exp2f(a0[3] + a1[3]);
        ps[p][0] += e0; ps[p][1] += e1; ps[p][2] += e2; ps[p][3] += e3;
        pk2[p][1][0] = cvt_pk(e0, e1);
        pk2[p][1][1] = cvt_pk(e2, e3);
      }
    }

    // -- P exchange on the VALU pipe (permlane32/16 swap) --
    union { unsigned u[4]; short8 s; } pa[2];
    #pragma unroll
    for (int p = 0; p < 2; ++p) {
      #pragma unroll
      for (int m = 0; m < 2; ++m) {
        unsigned x = pk2[p][0][m], y = pk2[p][1][m];
        asm("v_permlane32_swap_b32 %0, %1" : "+v"(x), "+v"(y));
        asm("v_permlane16_swap_b32 %0, %1" : "+v"(x), "+v"(y));
        pa[p].u[m]     = x;
        pa[p].u[2 + m] = y;
      }
    }

    // -- PV with SWAPPED operands: D[d-row][n-col] so the epilogue is
    //    float4 stores (lane (c,g): col n=c, rows d = dt*16+4g+0..3) --
    ao[0][0] = __builtin_amdgcn_mfma_f32_16x16x32_bf16(vf0, pa[0].s, ao[0][0], 0, 0, 0);
    ao[1][0] = __builtin_amdgcn_mfma_f32_16x16x32_bf16(vf0, pa[1].s, ao[1][0], 0, 0, 0);
    ao[0][1] = __builtin_amdgcn_mfma_f32_16x16x32_bf16(vf1, pa[0].s, ao[0][1], 0, 0, 0);
    ao[1][1] = __builtin_amdgcn_mfma_f32_16x16x32_bf16(vf1, pa[1].s, ao[1][1], 0, 0, 0);
    ao[0][2] = __builtin_amdgcn_mfma_f32_16x16x32_bf16(vf2, pa[0].s, ao[0][2], 0, 0, 0);
    ao[1][2] = __builtin_amdgcn_mfma_f32_16x16x32_bf16(vf2, pa[1].s, ao[1][2], 0, 0, 0);
    ao[0][3] = __builtin_amdgcn_mfma_f32_16x16x32_bf16(vf3, pa[0].s, ao[0][3], 0, 0, 0);
    ao[1][3] = __builtin_amdgcn_mfma_f32_16x16x32_bf16(vf3, pa[1].s, ao[1][3], 0, 0, 0);
  }

  // ---- softmax denominators + float4 epilogue ----
  #pragma unroll
  for (int p = 0; p < 2; ++p) {
    const int n0 = p * 128 + wave * 16;
    float sum = (ps[p][0] + ps[p][1]) + (ps[p][2] + ps[p][3]);
    sum += __shfl_xor(sum, 16);
    sum += __shfl_xor(sum, 32);
    const float rcp = __builtin_amdgcn_rcpf(sum);   // lane's own col n = c
    #pragma unroll
    for (int dt = 0; dt < 4; ++dt) {
      float4 o;
      o.x = ao[p][dt][0] * rcp;
      o.y = ao[p][dt][1] * rcp;
      o.z = ao[p][dt][2] * rcp;
      o.w = ao[p][dt][3] * rcp;
      *reinterpret_cast<float4*>(
          &O[base + (n0 + c) * 512 + dt * 16 + 4 * g]) = o;
    }
  }
#undef KREAD
#undef VREAD
}

extern "C" void kernel_launch(void* const* d_in, const int* in_sizes, int n_in,
                              void* d_out, int out_size, void* d_ws, size_t ws_size,
                              hipStream_t stream) {
  const float* Q = (const float*)d_in[0];
  const float* K = (const float*)d_in[1];
  const float* V = (const float*)d_in[2];
  float* O = (float*)d_out;
  attn_kernel<<<dim3(512), dim3(512), 0, stream>>>(Q, K, V, O);
}

// Round 11
// 34.460 us; speedup vs baseline: 1.4186x; 1.4186x over previous
//
#include <hip/hip_runtime.h>

// B=4, T=16, N=S=256, H=8, DK=DV=64, fp32 in/out.
// One block per (bt, h): 512 blocks x 512 threads (8 waves).
// Swapped QK^T (A=K, B=Q), no max-sub, scale*log2e folded into Q,
// permlane P exchange, V^T XOR bank-swizzle, plain coalesced stores.
// This round: SPLIT-BARRIER staging overlap. V global loads are issued
// before barrier-1 into registers; pass-0 QK^T (all 16 s-tiles) runs on
// K-only LDS while V loads fly; V->LDS written after, barrier-2, then a
// merged per-ks loop {PV0, QK^T-1, PV1} (K/V LDS fragments read once for
// pass1 PV+QKT; V shared by both passes' PV).

typedef short short8 __attribute__((ext_vector_type(8)));
typedef float floatx4 __attribute__((ext_vector_type(4)));

__device__ __forceinline__ unsigned cvt_pk(float lo, float hi) {
  unsigned r;
  asm("v_cvt_pk_bf16_f32 %0, %1, %2" : "=v"(r) : "v"(lo), "v"(hi));
  return r;
}

constexpr int KSTR  = 72;    // Klds row stride in shorts (144 B)
constexpr int VSTRW = 132;   // Vt row stride in u32 words (528 B)

__global__ __launch_bounds__(512, 4) void attn_kernel(
    const float* __restrict__ Q, const float* __restrict__ K,
    const float* __restrict__ V, float* __restrict__ O) {
  __shared__ __align__(16) short Klds[256 * KSTR];       // 36864 B
  __shared__ __align__(16) unsigned Vt32[64 * VSTRW];    // 33792 B (70656 total)

  const int inst = blockIdx.x;
  const int h    = inst & 7;
  const int bt   = inst >> 3;
  const int base = bt * (256 * 512) + h * 64;
  const int tid  = threadIdx.x;

  const int wave = tid >> 6;
  const int lane = tid & 63;
  const int c    = lane & 15;
  const int g    = lane >> 4;
  const int c4   = tid & 15;
  const int sQ   = tid >> 4;       // 0..31

  // ---- stage K: 256x64 fp32 -> bf16 LDS (interleaved load/cvt/write) ----
  {
    const float* Kb = K + base;
    #pragma unroll
    for (int i = 0; i < 8; ++i) {
      float4 v = *reinterpret_cast<const float4*>(Kb + (i * 32 + sQ) * 512 + c4 * 4);
      uint2 w;
      w.x = cvt_pk(v.x, v.y);
      w.y = cvt_pk(v.z, v.w);
      *reinterpret_cast<uint2*>(&Klds[(i * 32 + sQ) * KSTR + c4 * 4]) = w;
    }
  }

  // ---- issue V global loads into registers (consumed after pass-0 QKT) ----
  float4 vv0[4], vv1[4];
  {
    const float* Vb = V + base;
    #pragma unroll
    for (int i = 0; i < 4; ++i) {
      int sp = i * 32 + sQ;
      vv0[i] = *reinterpret_cast<const float4*>(Vb + (2 * sp) * 512 + c4 * 4);
      vv1[i] = *reinterpret_cast<const float4*>(Vb + (2 * sp + 1) * 512 + c4 * 4);
    }
  }

  // ---- Q fragments for BOTH passes, scaled by 0.125*log2(e) ----
  const float SCQ = 0.125f * 1.4426950408889634f;
  short8 qf[2][2];
  #pragma unroll
  for (int p = 0; p < 2; ++p) {
    #pragma unroll
    for (int ks2 = 0; ks2 < 2; ++ks2) {
      const float* qp =
          Q + base + (p * 128 + wave * 16 + c) * 512 + ks2 * 32 + g * 8;
      float4 a = *reinterpret_cast<const float4*>(qp);
      float4 b = *reinterpret_cast<const float4*>(qp + 4);
      union { unsigned u[4]; short8 s; } t;
      t.u[0] = cvt_pk(a.x * SCQ, a.y * SCQ);
      t.u[1] = cvt_pk(a.z * SCQ, a.w * SCQ);
      t.u[2] = cvt_pk(b.x * SCQ, b.y * SCQ);
      t.u[3] = cvt_pk(b.z * SCQ, b.w * SCQ);
      qf[p][ks2] = t.s;
    }
  }
  __syncthreads();   // barrier 1: K ready (V still in flight)

#define KREAD(t, half) \
  (*reinterpret_cast<const short8*>(&Klds[((t) * 16 + c) * KSTR + (half) * 32 + g * 8]))
#define VREAD(dt, ks) \
  (*reinterpret_cast<const short8*>(reinterpret_cast<const short*>( \
      &Vt32[((dt) * 16 + c) * VSTRW + \
            (((ks) * 16 + 4 * g) ^ (16 * ((dt) & 1) + (c & 12)))])))

  // ---- pass-0 QK^T over all 16 s-tiles (V loads land underneath) ----
  unsigned pk0[16][2];
  float ps0[4] = {0.f, 0.f, 0.f, 0.f};
  #pragma unroll
  for (int t = 0; t < 16; ++t) {
    short8 kf0 = KREAD(t, 0);
    short8 kf1 = KREAD(t, 1);
    floatx4 z = {0.f, 0.f, 0.f, 0.f};
    floatx4 a0 = __builtin_amdgcn_mfma_f32_16x16x32_bf16(kf0, qf[0][0], z, 0, 0, 0);
    floatx4 a1 = __builtin_amdgcn_mfma_f32_16x16x32_bf16(kf1, qf[0][1], z, 0, 0, 0);
    float e0 = exp2f(a0[0] + a1[0]);
    float e1 = exp2f(a0[1] + a1[1]);
    float e2 = exp2f(a0[2] + a1[2]);
    float e3 = exp2f(a0[3] + a1[3]);
    ps0[0] += e0; ps0[1] += e1; ps0[2] += e2; ps0[3] += e3;
    pk0[t][0] = cvt_pk(e0, e1);
    pk0[t][1] = cvt_pk(e2, e3);
  }

  // ---- now write V^T to LDS (XOR bank swizzle) ----
  #pragma unroll
  for (int i = 0; i < 4; ++i) {
    int sp  = i * 32 + sQ;
    int spw = sp ^ ((c4 & 7) << 2);
    #pragma unroll
    for (int k = 0; k < 4; ++k)
      Vt32[(c4 * 4 + k) * VSTRW + spw] = cvt_pk((&vv0[i].x)[k], (&vv1[i].x)[k]);
  }
  __syncthreads();   // barrier 2: V ready

  // ---- merged loop: {PV0, QK^T-1, PV1} per s-chunk of 32 ----
  floatx4 ao[2][4];
  #pragma unroll
  for (int p = 0; p < 2; ++p)
    #pragma unroll
    for (int dt = 0; dt < 4; ++dt) ao[p][dt] = floatx4{0.f, 0.f, 0.f, 0.f};
  float ps1[4] = {0.f, 0.f, 0.f, 0.f};

  #pragma unroll
  for (int ks = 0; ks < 8; ++ks) {
    // V fragments for this chunk (shared by both passes)
    short8 vf0 = VREAD(0, ks);
    short8 vf1 = VREAD(1, ks);
    short8 vf2 = VREAD(2, ks);
    short8 vf3 = VREAD(3, ks);

    // pass-0 P fragments from pk0 (VALU permlane exchange)
    union { unsigned u[4]; short8 s; } pa0;
    #pragma unroll
    for (int m = 0; m < 2; ++m) {
      unsigned x = pk0[2 * ks][m], y = pk0[2 * ks + 1][m];
      asm("v_permlane32_swap_b32 %0, %1" : "+v"(x), "+v"(y));
      asm("v_permlane16_swap_b32 %0, %1" : "+v"(x), "+v"(y));
      pa0.u[m]     = x;
      pa0.u[2 + m] = y;
    }

    // pass-1 QK^T for tiles 2ks, 2ks+1
    unsigned pk1[2][2];
    #pragma unroll
    for (int tt = 0; tt < 2; ++tt) {
      const int t = 2 * ks + tt;
      short8 kf0 = KREAD(t, 0);
      short8 kf1 = KREAD(t, 1);
      floatx4 z = {0.f, 0.f, 0.f, 0.f};
      floatx4 a0 = __builtin_amdgcn_mfma_f32_16x16x32_bf16(kf0, qf[1][0], z, 0, 0, 0);
      floatx4 a1 = __builtin_amdgcn_mfma_f32_16x16x32_bf16(kf1, qf[1][1], z, 0, 0, 0);
      float e0 = exp2f(a0[0] + a1[0]);
      float e1 = exp2f(a0[1] + a1[1]);
      float e2 = exp2f(a0[2] + a1[2]);
      float e3 = exp2f(a0[3] + a1[3]);
      ps1[0] += e0; ps1[1] += e1; ps1[2] += e2; ps1[3] += e3;
      pk1[tt][0] = cvt_pk(e0, e1);
      pk1[tt][1] = cvt_pk(e2, e3);
    }
    union { unsigned u[4]; short8 s; } pa1;
    #pragma unroll
    for (int m = 0; m < 2; ++m) {
      unsigned x = pk1[0][m], y = pk1[1][m];
      asm("v_permlane32_swap_b32 %0, %1" : "+v"(x), "+v"(y));
      asm("v_permlane16_swap_b32 %0, %1" : "+v"(x), "+v"(y));
      pa1.u[m]     = x;
      pa1.u[2 + m] = y;
    }

    // PV for both passes
    ao[0][0] = __builtin_amdgcn_mfma_f32_16x16x32_bf16(pa0.s, vf0, ao[0][0], 0, 0, 0);
    ao[1][0] = __builtin_amdgcn_mfma_f32_16x16x32_bf16(pa1.s, vf0, ao[1][0], 0, 0, 0);
    ao[0][1] = __builtin_amdgcn_mfma_f32_16x16x32_bf16(pa0.s, vf1, ao[0][1], 0, 0, 0);
    ao[1][1] = __builtin_amdgcn_mfma_f32_16x16x32_bf16(pa1.s, vf1, ao[1][1], 0, 0, 0);
    ao[0][2] = __builtin_amdgcn_mfma_f32_16x16x32_bf16(pa0.s, vf2, ao[0][2], 0, 0, 0);
    ao[1][2] = __builtin_amdgcn_mfma_f32_16x16x32_bf16(pa1.s, vf2, ao[1][2], 0, 0, 0);
    ao[0][3] = __builtin_amdgcn_mfma_f32_16x16x32_bf16(pa0.s, vf3, ao[0][3], 0, 0, 0);
    ao[1][3] = __builtin_amdgcn_mfma_f32_16x16x32_bf16(pa1.s, vf3, ao[1][3], 0, 0, 0);
  }

  // ---- softmax denominators + epilogue (coalesced 64B row segments) ----
  #pragma unroll
  for (int p = 0; p < 2; ++p) {
    const int n0 = p * 128 + wave * 16;
    float s4 = p == 0 ? (ps0[0] + ps0[1]) + (ps0[2] + ps0[3])
                      : (ps1[0] + ps1[1]) + (ps1[2] + ps1[3]);
    s4 += __shfl_xor(s4, 16);
    s4 += __shfl_xor(s4, 32);
    const float rcp = __builtin_amdgcn_rcpf(s4);
    float rcpv[4];
    #pragma unroll
    for (int r = 0; r < 4; ++r) rcpv[r] = __shfl(rcp, 4 * g + r);
    #pragma unroll
    for (int dt = 0; dt < 4; ++dt)
      #pragma unroll
      for (int r = 0; r < 4; ++r)
        O[base + (n0 + 4 * g + r) * 512 + dt * 16 + c] = ao[p][dt][r] * rcpv[r];
  }
#undef KREAD
#undef VREAD
}

extern "C" void kernel_launch(void* const* d_in, const int* in_sizes, int n_in,
                              void* d_out, int out_size, void* d_ws, size_t ws_size,
                              hipStream_t stream) {
  const float* Q = (const float*)d_in[0];
  const float* K = (const float*)d_in[1];
  const float* V = (const float*)d_in[2];
  float* O = (float*)d_out;
  attn_kernel<<<dim3(512), dim3(512), 0, stream>>>(Q, K, V, O);
}